// Round 3
// baseline (49.455 us; speedup 1.0000x reference)
//
#include <hip/hip_runtime.h>
#include <hip/hip_bf16.h>

// ResidualRotationWarpLayer: out[b,y,x,c] = bilinear(images[b], H_b warp of (x,y))
// H_b = diag(fx,fy,1) * R(q) * diag(fx,fy,1)^-1
// B=32, H=512, W=512, C=3, fp32.

#define IMG_H 512
#define IMG_W 512
#define IMG_C 3
#define NB    32

__global__ __launch_bounds__(256) void warp_kernel(
    const float* __restrict__ images,
    const float* __restrict__ focal,
    const float* __restrict__ q,
    float* __restrict__ out)
{
    const int b = blockIdx.z;
    const int y = blockIdx.y;
    const int xbase = blockIdx.x * 256;
    const int tid = threadIdx.x;

    __shared__ float sH[9];
    __shared__ float s_out[256 * 3];

    if (tid == 0) {
        // replicate reference op order for numerics
        float q0 = q[0], q1 = q[1], q2 = q[2], q3 = q[3];
        float s = sqrtf(2.0f / (q0*q0 + q1*q1 + q2*q2 + q3*q3));
        q0 *= s; q1 *= s; q2 *= s; q3 *= s;
        float R00 = 1.0f - q2*q2 - q3*q3;
        float R01 = q1*q2 - q3*q0;
        float R02 = q1*q3 + q2*q0;
        float R10 = q1*q2 + q3*q0;
        float R11 = 1.0f - q1*q1 - q3*q3;
        float R12 = q2*q3 - q1*q0;
        float R20 = q1*q3 - q2*q0;
        float R21 = q2*q3 + q1*q0;
        float R22 = 1.0f - q1*q1 - q2*q2;
        float d0 = focal[b*2 + 0];
        float d1 = focal[b*2 + 1];
        float d2 = 1.0f;
        sH[0] = (R00*d0)/d0; sH[1] = (R01*d0)/d1; sH[2] = (R02*d0)/d2;
        sH[3] = (R10*d1)/d0; sH[4] = (R11*d1)/d1; sH[5] = (R12*d1)/d2;
        sH[6] = (R20*d2)/d0; sH[7] = (R21*d2)/d1; sH[8] = (R22*d2)/d2;
    }
    __syncthreads();

    const float xs = (float)(xbase + tid) - 256.0f;   // W/2
    const float ys = (float)y - 256.0f;               // H/2

    const float h0 = sH[0], h1 = sH[1], h2 = sH[2];
    const float h3 = sH[3], h4 = sH[4], h5 = sH[5];
    const float h6 = sH[6], h7 = sH[7], h8 = sH[8];

    float p0 = h0*xs + h1*ys + h2;
    float p1 = h3*xs + h4*ys + h5;
    float p2 = h6*xs + h7*ys + h8;

    float xw = p0 / p2 + 256.0f;
    float yw = p1 / p2 + 256.0f;

    float x0f = floorf(xw);
    float y0f = floorf(yw);
    float wx = xw - x0f;
    float wy = yw - y0f;
    int x0 = (int)x0f;
    int y0 = (int)y0f;

    float w00 = (1.0f - wx) * (1.0f - wy);
    float w01 = wx * (1.0f - wy);
    float w10 = (1.0f - wx) * wy;
    float w11 = wx * wy;

    const float* img_b = images + (size_t)b * (IMG_H * IMG_W * IMG_C);

    float acc0 = 0.0f, acc1 = 0.0f, acc2 = 0.0f;

    #define CORNER(yi, xi, w) do {                                         \
        int _yi = (yi), _xi = (xi);                                        \
        bool _valid = (_xi >= 0) & (_xi <= IMG_W-1) &                      \
                      (_yi >= 0) & (_yi <= IMG_H-1);                       \
        int _yc = min(max(_yi, 0), IMG_H-1);                               \
        int _xc = min(max(_xi, 0), IMG_W-1);                               \
        const float* _p = img_b + ((size_t)_yc * IMG_W + _xc) * IMG_C;     \
        float _wv = _valid ? (w) : 0.0f;                                   \
        acc0 += _p[0] * _wv;                                               \
        acc1 += _p[1] * _wv;                                               \
        acc2 += _p[2] * _wv;                                               \
    } while (0)

    CORNER(y0,     x0,     w00);
    CORNER(y0,     x0 + 1, w01);
    CORNER(y0 + 1, x0,     w10);
    CORNER(y0 + 1, x0 + 1, w11);

    #undef CORNER

    // stage through LDS for fully coalesced, vectorized stores
    s_out[tid*3 + 0] = acc0;
    s_out[tid*3 + 1] = acc1;
    s_out[tid*3 + 2] = acc2;
    __syncthreads();

    // 256 px * 3 ch = 768 floats = 192 float4 per row-segment
    if (tid < 192) {
        float4 v = *reinterpret_cast<const float4*>(&s_out[tid * 4]);
        float4* outp = reinterpret_cast<float4*>(
            out + (((size_t)b * IMG_H + y) * IMG_W + xbase) * IMG_C);
        outp[tid] = v;
    }
}

extern "C" void kernel_launch(void* const* d_in, const int* in_sizes, int n_in,
                              void* d_out, int out_size, void* d_ws, size_t ws_size,
                              hipStream_t stream) {
    const float* images = (const float*)d_in[0];
    const float* focal  = (const float*)d_in[1];
    const float* q      = (const float*)d_in[2];
    float* out = (float*)d_out;

    dim3 grid(IMG_W / 256, IMG_H, NB);
    dim3 block(256);
    warp_kernel<<<grid, block, 0, stream>>>(images, focal, q, out);
}

// Round 4
// 37.941 us; speedup vs baseline: 1.3035x; 1.3035x over previous
//
#include <hip/hip_runtime.h>
#include <hip/hip_bf16.h>

// ResidualRotationWarpLayer: out[b,y,x,c] = bilinear(images[b], H_b warp of (x,y))
// H_b = diag(fx,fy,1) * R(q) * diag(fx,fy,1)^-1
// B=32, H=512, W=512, C=3, fp32.
//
// Grid: 1-D 32768 blocks, XCD-swizzled so each XCD (8 total) owns 4 complete
// images in y-major order -> bilinear's row-(y+1) reuse hits that XCD's L2
// (one image = 3.15 MB < 4 MB L2/XCD).

#define IMG_H 512
#define IMG_W 512
#define IMG_C 3
#define NB    32

__global__ __launch_bounds__(256) void warp_kernel(
    const float* __restrict__ images,
    const float* __restrict__ focal,
    const float* __restrict__ q,
    float* __restrict__ out)
{
    // --- XCD-aware tile remap (bijective; 32768 = 8 XCDs * 4096) ---
    const unsigned bid  = blockIdx.x;
    const unsigned xcd  = bid & 7u;          // round-robin dispatch -> XCD id
    const unsigned slot = bid >> 3;          // 0..4095 within XCD
    const unsigned virt = xcd * 4096u + slot;
    const int b        = (int)(virt >> 10);          // 1024 tiles per image
    const unsigned rem = virt & 1023u;
    const int y        = (int)(rem >> 1);
    const int xbase    = (int)(rem & 1u) * 256;

    const int tid = threadIdx.x;

    __shared__ float sH[9];
    __shared__ float s_out[256 * 3];

    if (tid == 0) {
        // replicate reference op order for numerics
        float q0 = q[0], q1 = q[1], q2 = q[2], q3 = q[3];
        float s = sqrtf(2.0f / (q0*q0 + q1*q1 + q2*q2 + q3*q3));
        q0 *= s; q1 *= s; q2 *= s; q3 *= s;
        float R00 = 1.0f - q2*q2 - q3*q3;
        float R01 = q1*q2 - q3*q0;
        float R02 = q1*q3 + q2*q0;
        float R10 = q1*q2 + q3*q0;
        float R11 = 1.0f - q1*q1 - q3*q3;
        float R12 = q2*q3 - q1*q0;
        float R20 = q1*q3 - q2*q0;
        float R21 = q2*q3 + q1*q0;
        float R22 = 1.0f - q1*q1 - q2*q2;
        float d0 = focal[b*2 + 0];
        float d1 = focal[b*2 + 1];
        float d2 = 1.0f;
        sH[0] = (R00*d0)/d0; sH[1] = (R01*d0)/d1; sH[2] = (R02*d0)/d2;
        sH[3] = (R10*d1)/d0; sH[4] = (R11*d1)/d1; sH[5] = (R12*d1)/d2;
        sH[6] = (R20*d2)/d0; sH[7] = (R21*d2)/d1; sH[8] = (R22*d2)/d2;
    }
    __syncthreads();

    const float xs = (float)(xbase + tid) - 256.0f;   // W/2
    const float ys = (float)y - 256.0f;               // H/2

    const float h0 = sH[0], h1 = sH[1], h2 = sH[2];
    const float h3 = sH[3], h4 = sH[4], h5 = sH[5];
    const float h6 = sH[6], h7 = sH[7], h8 = sH[8];

    float p0 = h0*xs + h1*ys + h2;
    float p1 = h3*xs + h4*ys + h5;
    float p2 = h6*xs + h7*ys + h8;

    float xw = p0 / p2 + 256.0f;
    float yw = p1 / p2 + 256.0f;

    float x0f = floorf(xw);
    float y0f = floorf(yw);
    float wx = xw - x0f;
    float wy = yw - y0f;
    int x0 = (int)x0f;
    int y0 = (int)y0f;

    float w00 = (1.0f - wx) * (1.0f - wy);
    float w01 = wx * (1.0f - wy);
    float w10 = (1.0f - wx) * wy;
    float w11 = wx * wy;

    const float* img_b = images + (size_t)b * (IMG_H * IMG_W * IMG_C);

    float acc0 = 0.0f, acc1 = 0.0f, acc2 = 0.0f;

    #define CORNER(yi, xi, w) do {                                         \
        int _yi = (yi), _xi = (xi);                                        \
        bool _valid = (_xi >= 0) & (_xi <= IMG_W-1) &                      \
                      (_yi >= 0) & (_yi <= IMG_H-1);                       \
        int _yc = min(max(_yi, 0), IMG_H-1);                               \
        int _xc = min(max(_xi, 0), IMG_W-1);                               \
        const float* _p = img_b + ((size_t)_yc * IMG_W + _xc) * IMG_C;     \
        float _wv = _valid ? (w) : 0.0f;                                   \
        acc0 += _p[0] * _wv;                                               \
        acc1 += _p[1] * _wv;                                               \
        acc2 += _p[2] * _wv;                                               \
    } while (0)

    CORNER(y0,     x0,     w00);
    CORNER(y0,     x0 + 1, w01);
    CORNER(y0 + 1, x0,     w10);
    CORNER(y0 + 1, x0 + 1, w11);

    #undef CORNER

    // stage through LDS for fully coalesced, vectorized stores
    s_out[tid*3 + 0] = acc0;
    s_out[tid*3 + 1] = acc1;
    s_out[tid*3 + 2] = acc2;
    __syncthreads();

    // 256 px * 3 ch = 768 floats = 192 float4 per row-segment
    if (tid < 192) {
        float4 v = *reinterpret_cast<const float4*>(&s_out[tid * 4]);
        float4* outp = reinterpret_cast<float4*>(
            out + (((size_t)b * IMG_H + y) * IMG_W + xbase) * IMG_C);
        outp[tid] = v;
    }
}

extern "C" void kernel_launch(void* const* d_in, const int* in_sizes, int n_in,
                              void* d_out, int out_size, void* d_ws, size_t ws_size,
                              hipStream_t stream) {
    const float* images = (const float*)d_in[0];
    const float* focal  = (const float*)d_in[1];
    const float* q      = (const float*)d_in[2];
    float* out = (float*)d_out;

    dim3 grid(32768);   // (W/256) * H * B = 2 * 512 * 32
    dim3 block(256);
    warp_kernel<<<grid, block, 0, stream>>>(images, focal, q, out);
}

// Round 6
// 33.298 us; speedup vs baseline: 1.4852x; 1.1394x over previous
//
#include <hip/hip_runtime.h>
#include <hip/hip_bf16.h>

// ResidualRotationWarpLayer: out[b,y,x,c] = bilinear(images[b], H_b warp of (x,y))
// H_b = diag(fx,fy,1) * R(q) * diag(fx,fy,1)^-1
// B=32, H=512, W=512, C=3, fp32.
//
// R6: same as R5 (2 px/thread, batched corner loads, XCD swizzle) with the
// nontemporal store switched to a clang ext_vector_type (HIP float4 is a
// class type the builtin rejects).

#define IMG_H 512
#define IMG_W 512
#define IMG_C 3
#define NB    32

typedef float f32x4 __attribute__((ext_vector_type(4)));

__global__ __launch_bounds__(256) void warp_kernel(
    const float* __restrict__ images,
    const float* __restrict__ focal,
    const float* __restrict__ q,
    float* __restrict__ out)
{
    // --- XCD-aware remap: 16384 blocks = 8 XCDs * 2048; each XCD owns 4 images
    const unsigned bid  = blockIdx.x;
    const unsigned xcd  = bid & 7u;
    const unsigned slot = bid >> 3;
    const unsigned virt = xcd * 2048u + slot;
    const int b = (int)(virt >> 9);      // 512 rows per image
    const int y = (int)(virt & 511u);

    const int tid = threadIdx.x;

    __shared__ float sH[9];
    __shared__ float s_out[IMG_W * IMG_C];   // 1536 floats = 6 KB

    if (tid == 0) {
        // replicate reference op order for numerics
        float q0 = q[0], q1 = q[1], q2 = q[2], q3 = q[3];
        float s = sqrtf(2.0f / (q0*q0 + q1*q1 + q2*q2 + q3*q3));
        q0 *= s; q1 *= s; q2 *= s; q3 *= s;
        float R00 = 1.0f - q2*q2 - q3*q3;
        float R01 = q1*q2 - q3*q0;
        float R02 = q1*q3 + q2*q0;
        float R10 = q1*q2 + q3*q0;
        float R11 = 1.0f - q1*q1 - q3*q3;
        float R12 = q2*q3 - q1*q0;
        float R20 = q1*q3 - q2*q0;
        float R21 = q2*q3 + q1*q0;
        float R22 = 1.0f - q1*q1 - q2*q2;
        float d0 = focal[b*2 + 0];
        float d1 = focal[b*2 + 1];
        sH[0] = (R00*d0)/d0; sH[1] = (R01*d0)/d1; sH[2] = (R02*d0);
        sH[3] = (R10*d1)/d0; sH[4] = (R11*d1)/d1; sH[5] = (R12*d1);
        sH[6] = R20/d0;      sH[7] = R21/d1;      sH[8] = R22;
    }
    __syncthreads();

    const float h0 = sH[0], h1 = sH[1], h2 = sH[2];
    const float h3 = sH[3], h4 = sH[4], h5 = sH[5];
    const float h6 = sH[6], h7 = sH[7], h8 = sH[8];

    const float ys = (float)y - 256.0f;
    const float* __restrict__ img_b = images + (unsigned)b * (IMG_H * IMG_W * IMG_C);

    // ---- per-pixel sampling; loads batched before math for ILP ----
    #define SAMPLE(PX, A0, A1, A2) do {                                        \
        const float xs = (float)(PX) - 256.0f;                                 \
        float p0 = h0*xs + h1*ys + h2;                                         \
        float p1 = h3*xs + h4*ys + h5;                                         \
        float p2 = h6*xs + h7*ys + h8;                                         \
        float xw = p0 / p2 + 256.0f;                                           \
        float yw = p1 / p2 + 256.0f;                                           \
        float x0f = floorf(xw), y0f = floorf(yw);                              \
        float wx = xw - x0f,   wy = yw - y0f;                                  \
        int x0 = (int)x0f, y0i = (int)y0f;                                     \
        int x1 = x0 + 1,  y1i = y0i + 1;                                       \
        bool vx0 = (x0 >= 0) & (x0 <= IMG_W-1);                                \
        bool vx1 = (x1 >= 0) & (x1 <= IMG_W-1);                                \
        bool vy0 = (y0i >= 0) & (y0i <= IMG_H-1);                              \
        bool vy1 = (y1i >= 0) & (y1i <= IMG_H-1);                              \
        unsigned xc0 = (unsigned)min(max(x0, 0), IMG_W-1);                     \
        unsigned xc1 = (unsigned)min(max(x1, 0), IMG_W-1);                     \
        unsigned yc0 = (unsigned)min(max(y0i, 0), IMG_H-1);                    \
        unsigned yc1 = (unsigned)min(max(y1i, 0), IMG_H-1);                    \
        const float* p00 = img_b + (yc0 * IMG_W + xc0) * IMG_C;                \
        const float* p01 = img_b + (yc0 * IMG_W + xc1) * IMG_C;                \
        const float* p10 = img_b + (yc1 * IMG_W + xc0) * IMG_C;                \
        const float* p11 = img_b + (yc1 * IMG_W + xc1) * IMG_C;                \
        float a00 = p00[0], a01 = p00[1], a02 = p00[2];                        \
        float b00 = p01[0], b01 = p01[1], b02 = p01[2];                        \
        float c00 = p10[0], c01 = p10[1], c02 = p10[2];                        \
        float d00 = p11[0], d01 = p11[1], d02 = p11[2];                        \
        float w00 = (vx0 & vy0) ? (1.0f - wx) * (1.0f - wy) : 0.0f;            \
        float w01 = (vx1 & vy0) ? wx * (1.0f - wy)          : 0.0f;            \
        float w10 = (vx0 & vy1) ? (1.0f - wx) * wy          : 0.0f;            \
        float w11 = (vx1 & vy1) ? wx * wy                   : 0.0f;            \
        A0 = a00*w00 + b00*w01 + c00*w10 + d00*w11;                            \
        A1 = a01*w00 + b01*w01 + c01*w10 + d01*w11;                            \
        A2 = a02*w00 + b02*w01 + c02*w10 + d02*w11;                            \
    } while (0)

    float o0a, o1a, o2a, o0b, o1b, o2b;
    SAMPLE(tid,        o0a, o1a, o2a);
    SAMPLE(tid + 256,  o0b, o1b, o2b);
    #undef SAMPLE

    // stage through LDS for coalesced, vectorized stores
    s_out[tid*3 + 0] = o0a;
    s_out[tid*3 + 1] = o1a;
    s_out[tid*3 + 2] = o2a;
    s_out[(tid + 256)*3 + 0] = o0b;
    s_out[(tid + 256)*3 + 1] = o1b;
    s_out[(tid + 256)*3 + 2] = o2b;
    __syncthreads();

    // 512 px * 3 ch = 1536 floats = 384 float4 per row
    f32x4* outp = reinterpret_cast<f32x4*>(
        out + ((unsigned)(b * IMG_H + y)) * (IMG_W * IMG_C));
    f32x4 v0 = *reinterpret_cast<const f32x4*>(&s_out[tid * 4]);
    __builtin_nontemporal_store(v0, &outp[tid]);
    if (tid < 128) {
        f32x4 v1 = *reinterpret_cast<const f32x4*>(&s_out[(256 + tid) * 4]);
        __builtin_nontemporal_store(v1, &outp[256 + tid]);
    }
}

extern "C" void kernel_launch(void* const* d_in, const int* in_sizes, int n_in,
                              void* d_out, int out_size, void* d_ws, size_t ws_size,
                              hipStream_t stream) {
    const float* images = (const float*)d_in[0];
    const float* focal  = (const float*)d_in[1];
    const float* q      = (const float*)d_in[2];
    float* out = (float*)d_out;

    dim3 grid(16384);   // H * B = 512 * 32 rows, one row per block
    dim3 block(256);
    warp_kernel<<<grid, block, 0, stream>>>(images, focal, q, out);
}